// Round 6
// baseline (1161.864 us; speedup 1.0000x reference)
//
#include <hip/hip_runtime.h>
#include <cstdint>

typedef _Float16 f16;
typedef f16 f16x2 __attribute__((ext_vector_type(2)));
typedef f16 f16x4 __attribute__((ext_vector_type(4)));
typedef f16 f16x8 __attribute__((ext_vector_type(8)));
typedef float f32x4 __attribute__((ext_vector_type(4)));

// problem constants (fixed by harness)
constexpr int D = 768;
constexpr int NTOK = 197;     // tokens per frame (1 cls + 196 spatial)
constexpr int BT = 64;        // B*T
constexpr int ROWS_A = BT * NTOK;      // 12608
constexpr int SEQ = 1569;              // T*H*W + 1
constexpr int ROWS_Y = 8 * SEQ;        // 12552
constexpr int DH = 3072;
constexpr int CW = 2304;               // 3*D
constexpr long Y_ELEMS = (long)ROWS_Y * D;     // 9639936
constexpr long LM_ELEMS = (long)BT * NTOK * NTOK;

// ---------------------------------------------------------------- convert
__global__ __launch_bounds__(256) void cvt_f16(const float* __restrict__ in,
                                               f16* __restrict__ out, int n4) {
  int i = blockIdx.x * 256 + threadIdx.x;
  if (i >= n4) return;
  const float4 v = *(const float4*)(in + (size_t)i * 4);
  f16x4 o = {(f16)v.x, (f16)v.y, (f16)v.z, (f16)v.w};
  *(f16x4*)(out + (size_t)i * 4) = o;
}

// --------------------------------------------- build xt (f16) + xn = LN(xt)
// one block per (bt, n) row; 192 threads x 4 floats = 768
__global__ __launch_bounds__(192) void build_xt_xn(
    const float* __restrict__ x, const float* __restrict__ g1,
    const float* __restrict__ be1, f16* __restrict__ xt, f16* __restrict__ xn) {
  const int rid = blockIdx.x;          // 0..12607
  const int bt = rid / NTOK, n = rid % NTOK;
  const int b = bt >> 3, t = bt & 7;
  const int src = (n == 0) ? b * SEQ : b * SEQ + 1 + (n - 1) * 8 + t;
  const int tid = threadIdx.x, d0 = tid * 4;
  const float4 v = *(const float4*)(x + (size_t)src * D + d0);
  float s = v.x + v.y + v.z + v.w;
  float q = v.x * v.x + v.y * v.y + v.z * v.z + v.w * v.w;
  const int lane = tid & 63, wv = tid >> 6;
  for (int off = 32; off; off >>= 1) {
    s += __shfl_xor(s, off);
    q += __shfl_xor(q, off);
  }
  __shared__ float red[2][3];
  if (lane == 0) { red[0][wv] = s; red[1][wv] = q; }
  __syncthreads();
  s = red[0][0] + red[0][1] + red[0][2];
  q = red[1][0] + red[1][1] + red[1][2];
  const float mean = s * (1.f / 768.f);
  const float var = q * (1.f / 768.f) - mean * mean;
  const float rs = rsqrtf(var + 1e-5f);
  const size_t ob = (size_t)rid * D + d0;
  f16x4 xo = {(f16)v.x, (f16)v.y, (f16)v.z, (f16)v.w};
  *(f16x4*)(xt + ob) = xo;
  const float4 gv = *(const float4*)(g1 + d0);
  const float4 bv = *(const float4*)(be1 + d0);
  f16x4 no = {(f16)((v.x - mean) * rs * gv.x + bv.x),
              (f16)((v.y - mean) * rs * gv.y + bv.y),
              (f16)((v.z - mean) * rs * gv.z + bv.z),
              (f16)((v.w - mean) * rs * gv.w + bv.w)};
  *(f16x4*)(xn + ob) = no;
}

// ---------------------------------------------------------------- GEMM
// C[M,N] = A[M,K] @ B[N,K]^T  (+ epilogue).  A,B f16 row-major, K%64==0.
// LDS-FREE: each wave loads its MFMA A/B fragments directly from global
// (f16x8 per lane, K-contiguous 16B -> 16 rows x 64B footprint per instr,
// same coalescing as staged loads). No __syncthreads in the K-loop, so the
// compiler software-pipelines with fine-grained vmcnt instead of the
// vmcnt(0)+barrier drain that capped the staged version at MfmaUtil~15%.
// Explicit depth-1 prefetch (unroll 2, a0/b0 <-> a1/b1).
constexpr int EPI_F16 = 0;            // Ch = acc
constexpr int EPI_F16_BIAS = 1;       // Ch = acc + bias
constexpr int EPI_SIG = 2;            // Cf = sigmoid(acc), [0,0] forced to 100
constexpr int EPI_F16_BIAS_GELU = 3;  // Ch = gelu(acc + bias)
constexpr int EPI_F32_BIAS_RES = 4;   // Cf = acc + bias + Res

template <int EPI>
__global__ __launch_bounds__(256, 2) void gemm_f16(
    const f16* __restrict__ A, const f16* __restrict__ B,
    const float* __restrict__ bias, float* __restrict__ Cf,
    f16* __restrict__ Ch, const float* __restrict__ Res, int M, int N, int K,
    int ldc, long sA, long sB, long sC) {
  constexpr int BM = 128, BN = 128;
  const int tid = threadIdx.x;
  const int bm = blockIdx.y * BM, bn = blockIdx.x * BN;
  const int z = blockIdx.z;
  A += (size_t)z * sA;
  B += (size_t)z * sB;
  const int lane = tid & 63, wave = tid >> 6;
  const int wm = (wave >> 1) * 64, wn = (wave & 1) * 64;
  const int l15 = lane & 15, quad = lane >> 4;

  // per-lane fragment element offsets (A-op layout: row=lane&15, k=quad*8+j)
  unsigned oA[4], oB[4];
#pragma unroll
  for (int i = 0; i < 4; i++) {
    int ra = bm + wm + i * 16 + l15; if (ra >= M) ra = M - 1;
    int cb = bn + wn + i * 16 + l15; if (cb >= N) cb = N - 1;
    oA[i] = (unsigned)ra * (unsigned)K + quad * 8;
    oB[i] = (unsigned)cb * (unsigned)K + quad * 8;
  }

  f32x4 acc[4][4] = {};
  f16x8 a0[4], b0[4], a1[4], b1[4];
#pragma unroll
  for (int i = 0; i < 4; i++) {
    a0[i] = *(const f16x8*)(A + oA[i]);
    b0[i] = *(const f16x8*)(B + oB[i]);
  }
  for (int kt = 0; kt < K; kt += 64) {
#pragma unroll
    for (int i = 0; i < 4; i++) {
      a1[i] = *(const f16x8*)(A + oA[i] + kt + 32);
      b1[i] = *(const f16x8*)(B + oB[i] + kt + 32);
    }
#pragma unroll
    for (int i = 0; i < 4; i++)
#pragma unroll
      for (int j = 0; j < 4; j++)
        acc[i][j] =
            __builtin_amdgcn_mfma_f32_16x16x32_f16(a0[i], b0[j], acc[i][j], 0, 0, 0);
    if (kt + 64 < K) {
#pragma unroll
      for (int i = 0; i < 4; i++) {
        a0[i] = *(const f16x8*)(A + oA[i] + kt + 64);
        b0[i] = *(const f16x8*)(B + oB[i] + kt + 64);
      }
    }
#pragma unroll
    for (int i = 0; i < 4; i++)
#pragma unroll
      for (int j = 0; j < 4; j++)
        acc[i][j] =
            __builtin_amdgcn_mfma_f32_16x16x32_f16(a1[i], b1[j], acc[i][j], 0, 0, 0);
  }

#pragma unroll
  for (int i = 0; i < 4; i++) {
#pragma unroll
    for (int j = 0; j < 4; j++) {
      const int col = bn + wn + j * 16 + l15;
      if (col >= N) continue;
#pragma unroll
      for (int r = 0; r < 4; r++) {
        const int row = bm + wm + i * 16 + quad * 4 + r;
        if (row >= M) continue;
        float v = acc[i][j][r];
        const size_t ci = (size_t)z * sC + (size_t)row * ldc + col;
        if constexpr (EPI == EPI_F16) {
          Ch[ci] = (f16)v;
        } else if constexpr (EPI == EPI_F16_BIAS) {
          Ch[ci] = (f16)(v + bias[col]);
        } else if constexpr (EPI == EPI_SIG) {
          if (row == 0 && col == 0) v = 100.f;
          Cf[ci] = 1.f / (1.f + __expf(-v));
        } else if constexpr (EPI == EPI_F16_BIAS_GELU) {
          // tanh-approx gelu via one v_exp_f32: gelu(u)=u*e/(e+1), e=exp(2t),
          // t=0.79788456*(u+0.044715u^3). max abs err ~3e-4.
          const float u = v + bias[col];
          const float t = u * (0.79788456f + 0.0356774081f * u * u);
          const float e = __expf(2.f * t);
          Ch[ci] = (f16)(u * (e / (e + 1.f)));
        } else if constexpr (EPI == EPI_F32_BIAS_RES) {
          Cf[ci] = v + bias[col] + Res[ci];
        }
      }
    }
  }
}

// ---------------------------------------------------------------- attention
// MFMA attention. One block per (bt, head); 4 waves, each wave owns 16-query
// tiles. S = Q K^T held in registers (13 x f32x4), register softmax + lm gate,
// P converted C-layout -> A-layout via per-wave 32-col LDS chunk, PV via MFMA.
__global__ __launch_bounds__(256, 2) void attn_kernel(
    const f16* __restrict__ qkv, const float* __restrict__ lm,
    f16* __restrict__ o) {
  __shared__ f16 Ks[208][72];     // 29952 B  (stride 144 B = 36 dwords)
  __shared__ f16 Vt[64][232];     // 29696 B  (stride 464 B = 116 dwords)
  __shared__ f16 Ps[4][16][40];   //  5120 B  (per-wave P chunk, 80 B = 20 dw)
  const int bh = blockIdx.x;
  const int bt = bh / 12, h = bh % 12;
  const int tid = threadIdx.x, lane = tid & 63, w = tid >> 6;
  const int l15 = lane & 15, quad = lane >> 4;
  const size_t base = (size_t)bt * NTOK * CW + (size_t)h * 64;

  // ---- stage K rows 0..196 (zeros for 197..207)
  for (int idx = tid; idx < 208 * 8; idx += 256) {
    const int r = idx >> 3, c = (idx & 7) * 8;
    f16x8 kv = {};
    if (r < NTOK) kv = *(const f16x8*)(qkv + base + (size_t)r * CW + 768 + c);
    *(f16x8*)&Ks[r][c] = kv;
  }
  // ---- stage V transposed: Vt[d][m]
  for (int cb = 0; cb < 8; cb++) {
    const int r = tid;
    if (r < NTOK) {
      const f16x8 vv = *(const f16x8*)(qkv + base + (size_t)r * CW + 1536 + cb * 8);
#pragma unroll
      for (int j = 0; j < 8; j++) Vt[cb * 8 + j][r] = vv[j];
    }
  }
  // zero-fill Vt cols 197..231 (prevents 0*NaN in PV MFMA)
  for (int idx = tid; idx < 64 * 35; idx += 256) {
    const int d = idx / 35, m = NTOK + idx % 35;
    Vt[d][m] = (f16)0.f;
  }
  __syncthreads();

  for (int nt = w; nt < 13; nt += 4) {
    // ---- S = Q K^T
    const int nq = nt * 16 + l15;
    const f16* qrow = qkv + base + (size_t)nq * CW;
    const f16x8 aq0 = *(const f16x8*)(qrow + quad * 8);
    const f16x8 aq1 = *(const f16x8*)(qrow + 32 + quad * 8);
    f32x4 S[13];
#pragma unroll
    for (int t = 0; t < 13; t++) {
      const f16x8 bk0 = *(const f16x8*)&Ks[t * 16 + l15][quad * 8];
      const f16x8 bk1 = *(const f16x8*)&Ks[t * 16 + l15][32 + quad * 8];
      f32x4 s = {};
      s = __builtin_amdgcn_mfma_f32_16x16x32_f16(aq0, bk0, s, 0, 0, 0);
      s = __builtin_amdgcn_mfma_f32_16x16x32_f16(aq1, bk1, s, 0, 0, 0);
      S[t] = s;
    }
    // ---- register softmax over m (rows n_loc = quad*4+r, col m = t*16+l15)
    float mx[4] = {-3e38f, -3e38f, -3e38f, -3e38f};
#pragma unroll
    for (int t = 0; t < 13; t++) {
      const int m = t * 16 + l15;
#pragma unroll
      for (int r = 0; r < 4; r++) {
        float v = (m < NTOK) ? S[t][r] * 0.125f : -1e30f;
        S[t][r] = v;
        mx[r] = fmaxf(mx[r], v);
      }
    }
#pragma unroll
    for (int off = 1; off < 16; off <<= 1)
#pragma unroll
      for (int r = 0; r < 4; r++) mx[r] = fmaxf(mx[r], __shfl_xor(mx[r], off));
    float den[4] = {0.f, 0.f, 0.f, 0.f};
#pragma unroll
    for (int t = 0; t < 13; t++)
#pragma unroll
      for (int r = 0; r < 4; r++) {
        const float e = __expf(S[t][r] - mx[r]);
        S[t][r] = e;
        den[r] += e;
      }
#pragma unroll
    for (int off = 1; off < 16; off <<= 1)
#pragma unroll
      for (int r = 0; r < 4; r++) den[r] += __shfl_xor(den[r], off);
    float inv[4];
#pragma unroll
    for (int r = 0; r < 4; r++) inv[r] = 1.f / den[r];
    // ---- gate with lm (guard both dims: lm buffer is exactly 197x197)
#pragma unroll
    for (int t = 0; t < 13; t++) {
      const int m = t * 16 + l15;
#pragma unroll
      for (int r = 0; r < 4; r++) {
        const int nrow = nt * 16 + quad * 4 + r;
        float g = 0.f;
        if (m < NTOK && nrow < NTOK)
          g = lm[((size_t)bt * NTOK + nrow) * NTOK + m];
        S[t][r] *= inv[r] * g;
      }
    }
    // ---- PV: chunk P (C-layout) through per-wave LDS to A-layout, MFMA
    f32x4 O[4] = {};
    for (int c = 0; c < 7; c++) {
      __builtin_amdgcn_wave_barrier();  // keep chunk writes after prior reads
#pragma unroll
      for (int tt = 0; tt < 2; tt++) {
        const int t = 2 * c + tt;
#pragma unroll
        for (int r = 0; r < 4; r++) {
          const f16 pv = (t < 13) ? (f16)S[t][r] : (f16)0.f;
          Ps[w][quad * 4 + r][tt * 16 + l15] = pv;
        }
      }
      __builtin_amdgcn_wave_barrier();  // writes before reads (in-order DS pipe)
      const f16x8 ap = *(const f16x8*)&Ps[w][l15][quad * 8];
#pragma unroll
      for (int dt = 0; dt < 4; dt++) {
        const f16x8 bv = *(const f16x8*)&Vt[dt * 16 + l15][c * 32 + quad * 8];
        O[dt] = __builtin_amdgcn_mfma_f32_16x16x32_f16(ap, bv, O[dt], 0, 0, 0);
      }
    }
    // ---- store O (C-layout: row n_loc = quad*4+r, col d = dt*16+l15)
#pragma unroll
    for (int dt = 0; dt < 4; dt++)
#pragma unroll
      for (int r = 0; r < 4; r++) {
        const int nrow = nt * 16 + quad * 4 + r;
        if (nrow < NTOK)
          o[((size_t)bt * NTOK + nrow) * D + h * 64 + dt * 16 + l15] =
              (f16)O[dt][r];
      }
  }
}

// ---------------------------------- y = x + scatter(proj_out); yn = LN(y)
__global__ __launch_bounds__(192) void scatter_y_ln(
    const float* __restrict__ x, const f16* __restrict__ po,
    const float* __restrict__ g2, const float* __restrict__ be2,
    float* __restrict__ y, f16* __restrict__ yn) {
  const int rid = blockIdx.x;  // 0..12551
  const int b = rid / SEQ, pos = rid % SEQ;
  const int tid = threadIdx.x, d0 = tid * 4;
  float4 v = *(const float4*)(x + (size_t)rid * D + d0);
  if (pos == 0) {
    float ax = 0, ay = 0, az = 0, aw = 0;
    for (int t = 0; t < 8; t++) {
      const f16x4 p = *(const f16x4*)(po + ((size_t)(b * 8 + t) * NTOK) * D + d0);
      ax += (float)p[0]; ay += (float)p[1]; az += (float)p[2]; aw += (float)p[3];
    }
    v.x += ax * 0.125f; v.y += ay * 0.125f; v.z += az * 0.125f; v.w += aw * 0.125f;
  } else {
    const int hw = (pos - 1) >> 3, t = (pos - 1) & 7;
    const f16x4 p =
        *(const f16x4*)(po + ((size_t)((b * 8 + t) * NTOK + 1 + hw)) * D + d0);
    v.x += (float)p[0]; v.y += (float)p[1]; v.z += (float)p[2]; v.w += (float)p[3];
  }
  *(float4*)(y + (size_t)rid * D + d0) = v;
  float s = v.x + v.y + v.z + v.w;
  float q = v.x * v.x + v.y * v.y + v.z * v.z + v.w * v.w;
  const int lane = tid & 63, wv = tid >> 6;
  for (int off = 32; off; off >>= 1) {
    s += __shfl_xor(s, off);
    q += __shfl_xor(q, off);
  }
  __shared__ float red[2][3];
  if (lane == 0) { red[0][wv] = s; red[1][wv] = q; }
  __syncthreads();
  s = red[0][0] + red[0][1] + red[0][2];
  q = red[1][0] + red[1][1] + red[1][2];
  const float mean = s * (1.f / 768.f);
  const float var = q * (1.f / 768.f) - mean * mean;
  const float rs = rsqrtf(var + 1e-5f);
  const float4 gv = *(const float4*)(g2 + d0);
  const float4 bv = *(const float4*)(be2 + d0);
  f16x4 no = {(f16)((v.x - mean) * rs * gv.x + bv.x),
              (f16)((v.y - mean) * rs * gv.y + bv.y),
              (f16)((v.z - mean) * rs * gv.z + bv.z),
              (f16)((v.w - mean) * rs * gv.w + bv.w)};
  *(f16x4*)(yn + (size_t)rid * D + d0) = no;
}

// ---------------------------------------------------------------- launch
extern "C" void kernel_launch(void* const* d_in, const int* in_sizes, int n_in,
                              void* d_out, int out_size, void* d_ws,
                              size_t ws_size, hipStream_t stream) {
  const float* x = (const float*)d_in[0];
  const float* W_mq = (const float*)d_in[1];
  const float* b_mq = (const float*)d_in[2];
  const float* W_mk = (const float*)d_in[3];
  const float* b_mk = (const float*)d_in[4];
  const float* g1 = (const float*)d_in[5];
  const float* be1 = (const float*)d_in[6];
  const float* W_qkv = (const float*)d_in[7];
  const float* W_proj = (const float*)d_in[8];
  const float* b_proj = (const float*)d_in[9];
  const float* g2 = (const float*)d_in[10];
  const float* be2 = (const float*)d_in[11];
  const float* W_fc1 = (const float*)d_in[12];
  const float* b_fc1 = (const float*)d_in[13];
  const float* W_fc2 = (const float*)d_in[14];
  const float* b_fc2 = (const float*)d_in[15];

  char* ws = (char*)d_ws;
  // weight pool (f16)
  size_t off = 0;
  auto alloc = [&](size_t bytes) {
    size_t o = off;
    off = (off + bytes + 255) & ~(size_t)255;
    return o;
  };
  const size_t o_wmq = alloc((size_t)D * D * 2);
  const size_t o_wmk = alloc((size_t)D * D * 2);
  const size_t o_wqkv = alloc((size_t)CW * D * 2);
  const size_t o_wproj = alloc((size_t)D * D * 2);
  const size_t o_wfc1 = alloc((size_t)DH * D * 2);
  const size_t o_wfc2 = alloc((size_t)D * DH * 2);
  const size_t o_xt = alloc((size_t)ROWS_A * D * 2);
  const size_t o_xn = alloc((size_t)ROWS_A * D * 2);
  const size_t o_qm = alloc((size_t)ROWS_A * D * 2);
  alloc((size_t)ROWS_A * D * 2);  // km right after qm
  const size_t o_km = o_qm + (size_t)ROWS_A * D * 2;
  // aliased regions (lifetimes disjoint):
  const size_t o_qkv = o_qm;                             // 58.1 MB, after lm done
  const size_t o_o = o_xn;                               // o after xn dead
  const size_t o_po = o_qm + (size_t)ROWS_A * CW * 2;    // after qkv
  const size_t o_yn = o_xt;                              // yn after xt dead
  const size_t o_h = o_qm;                               // h after qkv/po dead

  f16* wmq = (f16*)(ws + o_wmq);
  f16* wmk = (f16*)(ws + o_wmk);
  f16* wqkv = (f16*)(ws + o_wqkv);
  f16* wproj = (f16*)(ws + o_wproj);
  f16* wfc1 = (f16*)(ws + o_wfc1);
  f16* wfc2 = (f16*)(ws + o_wfc2);
  f16* xt = (f16*)(ws + o_xt);
  f16* xn = (f16*)(ws + o_xn);
  f16* qm = (f16*)(ws + o_qm);
  f16* km = (f16*)(ws + o_km);
  f16* qkv = (f16*)(ws + o_qkv);
  f16* oatt = (f16*)(ws + o_o);
  f16* po = (f16*)(ws + o_po);
  f16* yn = (f16*)(ws + o_yn);
  f16* h = (f16*)(ws + o_h);

  float* y_out = (float*)d_out;
  float* lm_out = (float*)d_out + Y_ELEMS;

  const dim3 blk(256);
  auto cvt = [&](const float* src, f16* dst, int n) {
    cvt_f16<<<dim3((n / 4 + 255) / 256), blk, 0, stream>>>(src, dst, n / 4);
  };
  cvt(W_mq, wmq, D * D);
  cvt(W_mk, wmk, D * D);
  cvt(W_qkv, wqkv, CW * D);
  cvt(W_proj, wproj, D * D);
  cvt(W_fc1, wfc1, DH * D);
  cvt(W_fc2, wfc2, D * DH);

  build_xt_xn<<<dim3(ROWS_A), dim3(192), 0, stream>>>(x, g1, be1, xt, xn);

  auto grd = [](int N_, int M_, int Z_) {
    return dim3((N_ + 127) / 128, (M_ + 127) / 128, Z_);
  };
  // qm / km (store f16, +bias)
  gemm_f16<EPI_F16_BIAS><<<grd(D, ROWS_A, 1), blk, 0, stream>>>(
      xt, wmq, b_mq, nullptr, qm, nullptr, ROWS_A, D, D, D, 0, 0, 0);
  gemm_f16<EPI_F16_BIAS><<<grd(D, ROWS_A, 1), blk, 0, stream>>>(
      xt, wmk, b_mk, nullptr, km, nullptr, ROWS_A, D, D, D, 0, 0, 0);
  // lm = sigmoid(qm km^T) batched, straight to d_out
  gemm_f16<EPI_SIG><<<grd(NTOK, NTOK, BT), blk, 0, stream>>>(
      qm, km, nullptr, lm_out, nullptr, nullptr, NTOK, NTOK, D, NTOK,
      (long)NTOK * D, (long)NTOK * D, (long)NTOK * NTOK);
  // qkv = xn @ W_qkv^T  (no bias)
  gemm_f16<EPI_F16><<<grd(CW, ROWS_A, 1), blk, 0, stream>>>(
      xn, wqkv, nullptr, nullptr, qkv, nullptr, ROWS_A, CW, D, CW, 0, 0, 0);
  // attention
  attn_kernel<<<dim3(BT * 12), blk, 0, stream>>>(qkv, lm_out, oatt);
  // proj (f16 out + bias)
  gemm_f16<EPI_F16_BIAS><<<grd(D, ROWS_A, 1), blk, 0, stream>>>(
      oatt, wproj, b_proj, nullptr, po, nullptr, ROWS_A, D, D, D, 0, 0, 0);
  // y = x + scatter(po); yn = LN(y)
  scatter_y_ln<<<dim3(ROWS_Y), dim3(192), 0, stream>>>(x, po, g2, be2, y_out, yn);
  // fc1 + gelu
  gemm_f16<EPI_F16_BIAS_GELU><<<grd(DH, ROWS_Y, 1), blk, 0, stream>>>(
      yn, wfc1, b_fc1, nullptr, h, nullptr, ROWS_Y, DH, D, DH, 0, 0, 0);
  // fc2 + bias + residual -> final y
  gemm_f16<EPI_F32_BIAS_RES><<<grd(D, ROWS_Y, 1), blk, 0, stream>>>(
      h, wfc2, b_fc2, y_out, nullptr, y_out, ROWS_Y, D, DH, D, 0, 0, 0);
  (void)in_sizes; (void)n_in; (void)out_size; (void)ws_size;
}

// Round 7
// 657.385 us; speedup vs baseline: 1.7674x; 1.7674x over previous
//
#include <hip/hip_runtime.h>
#include <cstdint>

typedef _Float16 f16;
typedef f16 f16x2 __attribute__((ext_vector_type(2)));
typedef f16 f16x4 __attribute__((ext_vector_type(4)));
typedef f16 f16x8 __attribute__((ext_vector_type(8)));
typedef float f32x4 __attribute__((ext_vector_type(4)));

// problem constants (fixed by harness)
constexpr int D = 768;
constexpr int NTOK = 197;     // tokens per frame (1 cls + 196 spatial)
constexpr int BT = 64;        // B*T
constexpr int ROWS_A = BT * NTOK;      // 12608
constexpr int SEQ = 1569;              // T*H*W + 1
constexpr int ROWS_Y = 8 * SEQ;        // 12552
constexpr int DH = 3072;
constexpr int CW = 2304;               // 3*D
constexpr long Y_ELEMS = (long)ROWS_Y * D;     // 9639936

// async global->LDS, 16B per lane; LDS dest = wave-uniform base + lane*16
__device__ __forceinline__ void gload_lds16(const f16* g, f16* l) {
  __builtin_amdgcn_global_load_lds(
      (const __attribute__((address_space(1))) void*)g,
      (__attribute__((address_space(3))) void*)l, 16, 0, 0);
}

// ---------------------------------------------------------------- convert
__global__ __launch_bounds__(256) void cvt_f16(const float* __restrict__ in,
                                               f16* __restrict__ out, int n4) {
  int i = blockIdx.x * 256 + threadIdx.x;
  if (i >= n4) return;
  const float4 v = *(const float4*)(in + (size_t)i * 4);
  f16x4 o = {(f16)v.x, (f16)v.y, (f16)v.z, (f16)v.w};
  *(f16x4*)(out + (size_t)i * 4) = o;
}

// concat two f32 vectors of length n -> out[0:n]=a, out[n:2n]=b
__global__ __launch_bounds__(256) void concat2_f32(const float* __restrict__ a,
                                                   const float* __restrict__ b,
                                                   float* __restrict__ o, int n) {
  int i = blockIdx.x * 256 + threadIdx.x;
  if (i < n) o[i] = a[i];
  else if (i < 2 * n) o[i] = b[i - n];
}

// --------------------------------------------- build xt (f16) + xn = LN(xt)
// one block per (bt, n) row; 192 threads x 4 floats = 768
__global__ __launch_bounds__(192) void build_xt_xn(
    const float* __restrict__ x, const float* __restrict__ g1,
    const float* __restrict__ be1, f16* __restrict__ xt, f16* __restrict__ xn) {
  const int rid = blockIdx.x;          // 0..12607
  const int bt = rid / NTOK, n = rid % NTOK;
  const int b = bt >> 3, t = bt & 7;
  const int src = (n == 0) ? b * SEQ : b * SEQ + 1 + (n - 1) * 8 + t;
  const int tid = threadIdx.x, d0 = tid * 4;
  const float4 v = *(const float4*)(x + (size_t)src * D + d0);
  float s = v.x + v.y + v.z + v.w;
  float q = v.x * v.x + v.y * v.y + v.z * v.z + v.w * v.w;
  const int lane = tid & 63, wv = tid >> 6;
  for (int off = 32; off; off >>= 1) {
    s += __shfl_xor(s, off);
    q += __shfl_xor(q, off);
  }
  __shared__ float red[2][3];
  if (lane == 0) { red[0][wv] = s; red[1][wv] = q; }
  __syncthreads();
  s = red[0][0] + red[0][1] + red[0][2];
  q = red[1][0] + red[1][1] + red[1][2];
  const float mean = s * (1.f / 768.f);
  const float var = q * (1.f / 768.f) - mean * mean;
  const float rs = rsqrtf(var + 1e-5f);
  const size_t ob = (size_t)rid * D + d0;
  f16x4 xo = {(f16)v.x, (f16)v.y, (f16)v.z, (f16)v.w};
  *(f16x4*)(xt + ob) = xo;
  const float4 gv = *(const float4*)(g1 + d0);
  const float4 bv = *(const float4*)(be1 + d0);
  f16x4 no = {(f16)((v.x - mean) * rs * gv.x + bv.x),
              (f16)((v.y - mean) * rs * gv.y + bv.y),
              (f16)((v.z - mean) * rs * gv.z + bv.z),
              (f16)((v.w - mean) * rs * gv.w + bv.w)};
  *(f16x4*)(xn + ob) = no;
}

// ---------------------------------------------------------------- GEMM
// C[M,N] = A[M,K] @ B[N,K]^T  (+ epilogue).  A,B f16 row-major, K%64==0.
// R2 structure (empirically best of R2-R5) + cross-barrier prefetch:
// double-buffered LDS, stage tile k+1 via global_load_lds BEFORE computing
// tile k, single __syncthreads per iter -> the vmcnt(0) drain at the barrier
// waits on a DMA that has had the whole ds_read+MFMA phase in flight.
constexpr int EPI_F16 = 0;            // Ch = acc
constexpr int EPI_F16_BIAS = 1;       // Ch = acc + bias
constexpr int EPI_SIG = 2;            // Cf = sigmoid(acc), [0,0] forced to 100
constexpr int EPI_F16_BIAS_GELU = 3;  // Ch = gelu(acc + bias)
constexpr int EPI_F32_BIAS_RES = 4;   // Cf = acc + bias + Res

template <int EPI>
__global__ __launch_bounds__(256, 3) void gemm_f16(
    const f16* __restrict__ A, const f16* __restrict__ B,
    const float* __restrict__ bias, float* __restrict__ Cf,
    f16* __restrict__ Ch, const float* __restrict__ Res, int M, int N, int K,
    int lda, int ldb, int ldc, long sA, long sB, long sC) {
  constexpr int BM = 128, BN = 128, BK = 32;
  __shared__ f16 As[2][BM][BK];   // 2 x 8 KB
  __shared__ f16 Bs[2][BN][BK];   // 2 x 8 KB
  const int tid = threadIdx.x;
  const int bm = blockIdx.y * BM, bn = blockIdx.x * BN;
  const int z = blockIdx.z;
  A += (size_t)z * sA;
  B += (size_t)z * sB;
  const int lane = tid & 63, wave = tid >> 6;
  const int wm = (wave >> 1) * 64, wn = (wave & 1) * 64;
  const int l15 = lane & 15, quad = lane >> 4;

  // staging: one wave-instr covers 16 rows (64 lanes x 16 B = 16 x 64 B).
  // wave w stages row-groups {w, w+4} of A and of B.
  const int gr = lane >> 2;         // row within group
  const int gc = (lane & 3) * 8;    // f16 col offset within row
  int a_row0 = bm + wave * 16 + gr;       if (a_row0 >= M) a_row0 = M - 1;
  int a_row1 = bm + (wave + 4) * 16 + gr; if (a_row1 >= M) a_row1 = M - 1;
  int b_row0 = bn + wave * 16 + gr;       if (b_row0 >= N) b_row0 = N - 1;
  int b_row1 = bn + (wave + 4) * 16 + gr; if (b_row1 >= N) b_row1 = N - 1;
  const f16* ap0 = A + (size_t)a_row0 * lda + gc;
  const f16* ap1 = A + (size_t)a_row1 * lda + gc;
  const f16* bp0 = B + (size_t)b_row0 * ldb + gc;
  const f16* bp1 = B + (size_t)b_row1 * ldb + gc;

  f32x4 acc[4][4] = {};

  auto stage = [&](int buf, int k) {
    gload_lds16(ap0 + k, &As[buf][wave * 16][0]);
    gload_lds16(ap1 + k, &As[buf][(wave + 4) * 16][0]);
    gload_lds16(bp0 + k, &Bs[buf][wave * 16][0]);
    gload_lds16(bp1 + k, &Bs[buf][(wave + 4) * 16][0]);
  };
  auto compute = [&](int buf) {
    f16x8 af[4], bf[4];
#pragma unroll
    for (int i = 0; i < 4; i++) {
      af[i] = *(const f16x8*)&As[buf][wm + i * 16 + l15][quad * 8];
      bf[i] = *(const f16x8*)&Bs[buf][wn + i * 16 + l15][quad * 8];
    }
#pragma unroll
    for (int i = 0; i < 4; i++)
#pragma unroll
      for (int j = 0; j < 4; j++)
        acc[i][j] =
            __builtin_amdgcn_mfma_f32_16x16x32_f16(af[i], bf[j], acc[i][j], 0, 0, 0);
  };

  stage(0, 0);
  __syncthreads();
  // K/BK is even for all our shapes (768/32=24, 3072/32=96)
  for (int kt = 0; kt < K; kt += 2 * BK) {
    stage(1, kt + BK);            // prefetch while computing buf0
    compute(0);
    __syncthreads();              // drains prefetch DMA + buf0 reads
    if (kt + 2 * BK < K) stage(0, kt + 2 * BK);
    compute(1);
    __syncthreads();
  }

#pragma unroll
  for (int i = 0; i < 4; i++) {
#pragma unroll
    for (int j = 0; j < 4; j++) {
      const int col = bn + wn + j * 16 + l15;
      if (col >= N) continue;
#pragma unroll
      for (int r = 0; r < 4; r++) {
        const int row = bm + wm + i * 16 + quad * 4 + r;
        if (row >= M) continue;
        float v = acc[i][j][r];
        const size_t ci = (size_t)z * sC + (size_t)row * ldc + col;
        if constexpr (EPI == EPI_F16) {
          Ch[ci] = (f16)v;
        } else if constexpr (EPI == EPI_F16_BIAS) {
          Ch[ci] = (f16)(v + bias[col]);
        } else if constexpr (EPI == EPI_SIG) {
          if (row == 0 && col == 0) v = 100.f;
          Cf[ci] = 1.f / (1.f + __expf(-v));
        } else if constexpr (EPI == EPI_F16_BIAS_GELU) {
          // tanh-approx gelu via one v_exp_f32 (validated R3-R5, err ~3e-4)
          const float u = v + bias[col];
          const float t = u * (0.79788456f + 0.0356774081f * u * u);
          const float e = __expf(2.f * t);
          Ch[ci] = (f16)(u * (e / (e + 1.f)));
        } else if constexpr (EPI == EPI_F32_BIAS_RES) {
          Cf[ci] = v + bias[col] + Res[ci];
        }
      }
    }
  }
}

// ---------------------------------------------------------------- attention
// MFMA attention. One block per (bt, head); 4 waves, each wave owns 16-query
// tiles. S = Q K^T held in registers (13 x f32x4), register softmax + lm gate,
// P converted C-layout -> A-layout via per-wave 32-col LDS chunk, PV via MFMA.
__global__ __launch_bounds__(256, 2) void attn_kernel(
    const f16* __restrict__ qkv, const float* __restrict__ lm,
    f16* __restrict__ o) {
  __shared__ f16 Ks[208][72];     // 29952 B  (stride 144 B = 36 dwords)
  __shared__ f16 Vt[64][232];     // 29696 B  (stride 464 B = 116 dwords)
  __shared__ f16 Ps[4][16][40];   //  5120 B  (per-wave P chunk, 80 B = 20 dw)
  const int bh = blockIdx.x;
  const int bt = bh / 12, h = bh % 12;
  const int tid = threadIdx.x, lane = tid & 63, w = tid >> 6;
  const int l15 = lane & 15, quad = lane >> 4;
  const size_t base = (size_t)bt * NTOK * CW + (size_t)h * 64;

  // ---- stage K rows 0..196 (zeros for 197..207)
  for (int idx = tid; idx < 208 * 8; idx += 256) {
    const int r = idx >> 3, c = (idx & 7) * 8;
    f16x8 kv = {};
    if (r < NTOK) kv = *(const f16x8*)(qkv + base + (size_t)r * CW + 768 + c);
    *(f16x8*)&Ks[r][c] = kv;
  }
  // ---- stage V transposed: Vt[d][m]
  for (int cb = 0; cb < 8; cb++) {
    const int r = tid;
    if (r < NTOK) {
      const f16x8 vv = *(const f16x8*)(qkv + base + (size_t)r * CW + 1536 + cb * 8);
#pragma unroll
      for (int j = 0; j < 8; j++) Vt[cb * 8 + j][r] = vv[j];
    }
  }
  // zero-fill Vt cols 197..231 (prevents 0*NaN in PV MFMA)
  for (int idx = tid; idx < 64 * 35; idx += 256) {
    const int d = idx / 35, m = NTOK + idx % 35;
    Vt[d][m] = (f16)0.f;
  }
  __syncthreads();

  for (int nt = w; nt < 13; nt += 4) {
    // ---- S = Q K^T
    const int nq = nt * 16 + l15;
    const f16* qrow = qkv + base + (size_t)nq * CW;
    const f16x8 aq0 = *(const f16x8*)(qrow + quad * 8);
    const f16x8 aq1 = *(const f16x8*)(qrow + 32 + quad * 8);
    f32x4 S[13];
#pragma unroll
    for (int t = 0; t < 13; t++) {
      const f16x8 bk0 = *(const f16x8*)&Ks[t * 16 + l15][quad * 8];
      const f16x8 bk1 = *(const f16x8*)&Ks[t * 16 + l15][32 + quad * 8];
      f32x4 s = {};
      s = __builtin_amdgcn_mfma_f32_16x16x32_f16(aq0, bk0, s, 0, 0, 0);
      s = __builtin_amdgcn_mfma_f32_16x16x32_f16(aq1, bk1, s, 0, 0, 0);
      S[t] = s;
    }
    // ---- register softmax over m (rows n_loc = quad*4+r, col m = t*16+l15)
    float mx[4] = {-3e38f, -3e38f, -3e38f, -3e38f};
#pragma unroll
    for (int t = 0; t < 13; t++) {
      const int m = t * 16 + l15;
#pragma unroll
      for (int r = 0; r < 4; r++) {
        float v = (m < NTOK) ? S[t][r] * 0.125f : -1e30f;
        S[t][r] = v;
        mx[r] = fmaxf(mx[r], v);
      }
    }
#pragma unroll
    for (int off = 1; off < 16; off <<= 1)
#pragma unroll
      for (int r = 0; r < 4; r++) mx[r] = fmaxf(mx[r], __shfl_xor(mx[r], off));
    float den[4] = {0.f, 0.f, 0.f, 0.f};
#pragma unroll
    for (int t = 0; t < 13; t++)
#pragma unroll
      for (int r = 0; r < 4; r++) {
        const float e = __expf(S[t][r] - mx[r]);
        S[t][r] = e;
        den[r] += e;
      }
#pragma unroll
    for (int off = 1; off < 16; off <<= 1)
#pragma unroll
      for (int r = 0; r < 4; r++) den[r] += __shfl_xor(den[r], off);
    float inv[4];
#pragma unroll
    for (int r = 0; r < 4; r++) inv[r] = 1.f / den[r];
    // ---- gate with lm (guard both dims: lm buffer is exactly 197x197)
#pragma unroll
    for (int t = 0; t < 13; t++) {
      const int m = t * 16 + l15;
#pragma unroll
      for (int r = 0; r < 4; r++) {
        const int nrow = nt * 16 + quad * 4 + r;
        float g = 0.f;
        if (m < NTOK && nrow < NTOK)
          g = lm[((size_t)bt * NTOK + nrow) * NTOK + m];
        S[t][r] *= inv[r] * g;
      }
    }
    // ---- PV: chunk P (C-layout) through per-wave LDS to A-layout, MFMA
    f32x4 O[4] = {};
    for (int c = 0; c < 7; c++) {
      __builtin_amdgcn_wave_barrier();  // keep chunk writes after prior reads
#pragma unroll
      for (int tt = 0; tt < 2; tt++) {
        const int t = 2 * c + tt;
#pragma unroll
        for (int r = 0; r < 4; r++) {
          const f16 pv = (t < 13) ? (f16)S[t][r] : (f16)0.f;
          Ps[w][quad * 4 + r][tt * 16 + l15] = pv;
        }
      }
      __builtin_amdgcn_wave_barrier();  // writes before reads (in-order DS pipe)
      const f16x8 ap = *(const f16x8*)&Ps[w][l15][quad * 8];
#pragma unroll
      for (int dt = 0; dt < 4; dt++) {
        const f16x8 bv = *(const f16x8*)&Vt[dt * 16 + l15][c * 32 + quad * 8];
        O[dt] = __builtin_amdgcn_mfma_f32_16x16x32_f16(ap, bv, O[dt], 0, 0, 0);
      }
    }
    // ---- store O (C-layout: row n_loc = quad*4+r, col d = dt*16+l15)
#pragma unroll
    for (int dt = 0; dt < 4; dt++)
#pragma unroll
      for (int r = 0; r < 4; r++) {
        const int nrow = nt * 16 + quad * 4 + r;
        if (nrow < NTOK)
          o[((size_t)bt * NTOK + nrow) * D + h * 64 + dt * 16 + l15] =
              (f16)O[dt][r];
      }
  }
}

// ---------------------------------- y = x + scatter(proj_out); yn = LN(y)
__global__ __launch_bounds__(192) void scatter_y_ln(
    const float* __restrict__ x, const f16* __restrict__ po,
    const float* __restrict__ g2, const float* __restrict__ be2,
    float* __restrict__ y, f16* __restrict__ yn) {
  const int rid = blockIdx.x;  // 0..12551
  const int b = rid / SEQ, pos = rid % SEQ;
  const int tid = threadIdx.x, d0 = tid * 4;
  float4 v = *(const float4*)(x + (size_t)rid * D + d0);
  if (pos == 0) {
    float ax = 0, ay = 0, az = 0, aw = 0;
    for (int t = 0; t < 8; t++) {
      const f16x4 p = *(const f16x4*)(po + ((size_t)(b * 8 + t) * NTOK) * D + d0);
      ax += (float)p[0]; ay += (float)p[1]; az += (float)p[2]; aw += (float)p[3];
    }
    v.x += ax * 0.125f; v.y += ay * 0.125f; v.z += az * 0.125f; v.w += aw * 0.125f;
  } else {
    const int hw = (pos - 1) >> 3, t = (pos - 1) & 7;
    const f16x4 p =
        *(const f16x4*)(po + ((size_t)((b * 8 + t) * NTOK + 1 + hw)) * D + d0);
    v.x += (float)p[0]; v.y += (float)p[1]; v.z += (float)p[2]; v.w += (float)p[3];
  }
  *(float4*)(y + (size_t)rid * D + d0) = v;
  float s = v.x + v.y + v.z + v.w;
  float q = v.x * v.x + v.y * v.y + v.z * v.z + v.w * v.w;
  const int lane = tid & 63, wv = tid >> 6;
  for (int off = 32; off; off >>= 1) {
    s += __shfl_xor(s, off);
    q += __shfl_xor(q, off);
  }
  __shared__ float red[2][3];
  if (lane == 0) { red[0][wv] = s; red[1][wv] = q; }
  __syncthreads();
  s = red[0][0] + red[0][1] + red[0][2];
  q = red[1][0] + red[1][1] + red[1][2];
  const float mean = s * (1.f / 768.f);
  const float var = q * (1.f / 768.f) - mean * mean;
  const float rs = rsqrtf(var + 1e-5f);
  const float4 gv = *(const float4*)(g2 + d0);
  const float4 bv = *(const float4*)(be2 + d0);
  f16x4 no = {(f16)((v.x - mean) * rs * gv.x + bv.x),
              (f16)((v.y - mean) * rs * gv.y + bv.y),
              (f16)((v.z - mean) * rs * gv.z + bv.z),
              (f16)((v.w - mean) * rs * gv.w + bv.w)};
  *(f16x4*)(yn + (size_t)rid * D + d0) = no;
}

// ---------------------------------------------------------------- launch
extern "C" void kernel_launch(void* const* d_in, const int* in_sizes, int n_in,
                              void* d_out, int out_size, void* d_ws,
                              size_t ws_size, hipStream_t stream) {
  const float* x = (const float*)d_in[0];
  const float* W_mq = (const float*)d_in[1];
  const float* b_mq = (const float*)d_in[2];
  const float* W_mk = (const float*)d_in[3];
  const float* b_mk = (const float*)d_in[4];
  const float* g1 = (const float*)d_in[5];
  const float* be1 = (const float*)d_in[6];
  const float* W_qkv = (const float*)d_in[7];
  const float* W_proj = (const float*)d_in[8];
  const float* b_proj = (const float*)d_in[9];
  const float* g2 = (const float*)d_in[10];
  const float* be2 = (const float*)d_in[11];
  const float* W_fc1 = (const float*)d_in[12];
  const float* b_fc1 = (const float*)d_in[13];
  const float* W_fc2 = (const float*)d_in[14];
  const float* b_fc2 = (const float*)d_in[15];

  char* ws = (char*)d_ws;
  size_t off = 0;
  auto alloc = [&](size_t bytes) {
    size_t o = off;
    off = (off + bytes + 255) & ~(size_t)255;
    return o;
  };
  const size_t o_wmqk = alloc((size_t)2 * D * D * 2);   // [W_mq; W_mk] stacked
  const size_t o_bmqk = alloc((size_t)2 * D * 4);       // [b_mq; b_mk] f32
  const size_t o_wqkv = alloc((size_t)CW * D * 2);
  const size_t o_wproj = alloc((size_t)D * D * 2);
  const size_t o_wfc1 = alloc((size_t)DH * D * 2);
  const size_t o_wfc2 = alloc((size_t)D * DH * 2);
  const size_t o_xt = alloc((size_t)ROWS_A * D * 2);
  const size_t o_xn = alloc((size_t)ROWS_A * D * 2);
  const size_t o_big = alloc((size_t)ROWS_A * CW * 2);  // qmkm, later qkv
  const size_t o_po = alloc((size_t)ROWS_A * D * 2);
  // aliases (lifetimes disjoint):
  const size_t o_qmkm = o_big;  // ROWS_A x 1536 f16 (38.7 MB < 58 MB)
  const size_t o_qkv = o_big;   // after lm done
  const size_t o_o = o_xn;      // attn out after xn dead
  const size_t o_yn = o_xt;     // yn after xt dead
  const size_t o_h = o_big;     // h (77.4 MB) spans big+po after both dead

  f16* wmqk = (f16*)(ws + o_wmqk);
  float* bmqk = (float*)(ws + o_bmqk);
  f16* wqkv = (f16*)(ws + o_wqkv);
  f16* wproj = (f16*)(ws + o_wproj);
  f16* wfc1 = (f16*)(ws + o_wfc1);
  f16* wfc2 = (f16*)(ws + o_wfc2);
  f16* xt = (f16*)(ws + o_xt);
  f16* xn = (f16*)(ws + o_xn);
  f16* qmkm = (f16*)(ws + o_qmkm);
  f16* qkv = (f16*)(ws + o_qkv);
  f16* oatt = (f16*)(ws + o_o);
  f16* po = (f16*)(ws + o_po);
  f16* yn = (f16*)(ws + o_yn);
  f16* h = (f16*)(ws + o_h);

  float* y_out = (float*)d_out;
  float* lm_out = (float*)d_out + Y_ELEMS;

  const dim3 blk(256);
  auto cvt = [&](const float* src, f16* dst, int n) {
    cvt_f16<<<dim3((n / 4 + 255) / 256), blk, 0, stream>>>(src, dst, n / 4);
  };
  cvt(W_mq, wmqk, D * D);
  cvt(W_mk, wmqk + (size_t)D * D, D * D);
  cvt(W_qkv, wqkv, CW * D);
  cvt(W_proj, wproj, D * D);
  cvt(W_fc1, wfc1, DH * D);
  cvt(W_fc2, wfc2, D * DH);
  concat2_f32<<<dim3(6), blk, 0, stream>>>(b_mq, b_mk, bmqk, D);

  build_xt_xn<<<dim3(ROWS_A), dim3(192), 0, stream>>>(x, g1, be1, xt, xn);

  auto grd = [](int N_, int M_, int Z_) {
    return dim3((N_ + 127) / 128, (M_ + 127) / 128, Z_);
  };
  // [qm|km] = xt @ [W_mq;W_mk]^T + [b_mq;b_mk]   (one GEMM, N=1536)
  gemm_f16<EPI_F16_BIAS><<<grd(2 * D, ROWS_A, 1), blk, 0, stream>>>(
      xt, wmqk, bmqk, nullptr, qmkm, nullptr, ROWS_A, 2 * D, D, D, D, 2 * D,
      0, 0, 0);
  // lm = sigmoid(qm km^T) batched, straight to d_out
  gemm_f16<EPI_SIG><<<grd(NTOK, NTOK, BT), blk, 0, stream>>>(
      qmkm, qmkm + D, nullptr, lm_out, nullptr, nullptr, NTOK, NTOK, D,
      2 * D, 2 * D, NTOK, (long)NTOK * 2 * D, (long)NTOK * 2 * D,
      (long)NTOK * NTOK);
  // qkv = xn @ W_qkv^T  (no bias)
  gemm_f16<EPI_F16><<<grd(CW, ROWS_A, 1), blk, 0, stream>>>(
      xn, wqkv, nullptr, nullptr, qkv, nullptr, ROWS_A, CW, D, D, D, CW,
      0, 0, 0);
  // attention
  attn_kernel<<<dim3(BT * 12), blk, 0, stream>>>(qkv, lm_out, oatt);
  // proj (f16 out + bias)
  gemm_f16<EPI_F16_BIAS><<<grd(D, ROWS_A, 1), blk, 0, stream>>>(
      oatt, wproj, b_proj, nullptr, po, nullptr, ROWS_A, D, D, D, D, D,
      0, 0, 0);
  // y = x + scatter(po); yn = LN(y)
  scatter_y_ln<<<dim3(ROWS_Y), dim3(192), 0, stream>>>(x, po, g2, be2, y_out, yn);
  // fc1 + gelu
  gemm_f16<EPI_F16_BIAS_GELU><<<grd(DH, ROWS_Y, 1), blk, 0, stream>>>(
      yn, wfc1, b_fc1, nullptr, h, nullptr, ROWS_Y, DH, D, D, D, DH, 0, 0, 0);
  // fc2 + bias + residual -> final y
  gemm_f16<EPI_F32_BIAS_RES><<<grd(D, ROWS_Y, 1), blk, 0, stream>>>(
      h, wfc2, b_fc2, y_out, nullptr, y_out, ROWS_Y, D, DH, DH, DH, D,
      0, 0, 0);
  (void)in_sizes; (void)n_in; (void)out_size; (void)ws_size;
}